// Round 1
// baseline (1017.944 us; speedup 1.0000x reference)
//
#include <hip/hip_runtime.h>

#define C 128
#define EPS 1e-5f
#define SCAN_TILE 4096   // 1024 threads x 4 elements

// ---------------- combined degree count over both edge types ----------------
// bucket: dst in [0,NU) for iu edges, NU + dst for ui edges.
__global__ __launch_bounds__(256) void count_kernel(
    const int* __restrict__ ei_iu, const int* __restrict__ ei_ui,
    int* __restrict__ cnt, int E, int NU)
{
    int t = blockIdx.x * blockDim.x + threadIdx.x;
    if (t < E)            atomicAdd(&cnt[ei_iu[E + t]], 1);
    else if (t < 2 * E)   atomicAdd(&cnt[NU + ei_ui[E + (t - E)]], 1);
}

// ---------------- 3-phase multiblock exclusive scan ----------------
__global__ __launch_bounds__(1024) void scan_partials(
    const int* __restrict__ cnt, int* __restrict__ partials, int NTOT)
{
    int base = blockIdx.x * SCAN_TILE + threadIdx.x * 4;
    int s = 0;
    #pragma unroll
    for (int k = 0; k < 4; ++k)
        if (base + k < NTOT) s += cnt[base + k];
    #pragma unroll
    for (int off = 32; off > 0; off >>= 1) s += __shfl_xor(s, off, 64);
    __shared__ int ws[16];
    int wave = threadIdx.x >> 6;
    if ((threadIdx.x & 63) == 0) ws[wave] = s;
    __syncthreads();
    if (threadIdx.x == 0) {
        int tot = 0;
        for (int i = 0; i < 16; ++i) tot += ws[i];
        partials[blockIdx.x] = tot;
    }
}

__global__ __launch_bounds__(1024) void scan_spine(
    int* __restrict__ partials, int* __restrict__ rp, int NPART, int NTOT)
{
    __shared__ int lds[1024];
    int t = threadIdx.x;
    lds[t] = (t < NPART) ? partials[t] : 0;
    __syncthreads();
    for (int off = 1; off < 1024; off <<= 1) {
        int v = (t >= off) ? lds[t - off] : 0;
        __syncthreads();
        lds[t] += v;
        __syncthreads();
    }
    if (t < NPART) partials[t] = (t == 0) ? 0 : lds[t - 1];
    if (t == 0) rp[NTOT] = lds[1023];   // grand total (zero-padded scan)
}

__global__ __launch_bounds__(1024) void scan_write(
    const int* __restrict__ cnt, const int* __restrict__ partials,
    int* __restrict__ rp, int* __restrict__ cur, int NTOT)
{
    __shared__ int lds[1024];
    int t = threadIdx.x;
    int base = blockIdx.x * SCAN_TILE + t * 4;
    int v0 = 0, v1 = 0, v2 = 0, v3 = 0;
    if (base + 0 < NTOT) v0 = cnt[base + 0];
    if (base + 1 < NTOT) v1 = cnt[base + 1];
    if (base + 2 < NTOT) v2 = cnt[base + 2];
    if (base + 3 < NTOT) v3 = cnt[base + 3];
    lds[t] = v0 + v1 + v2 + v3;
    __syncthreads();
    for (int off = 1; off < 1024; off <<= 1) {
        int v = (t >= off) ? lds[t - off] : 0;
        __syncthreads();
        lds[t] += v;
        __syncthreads();
    }
    int p = partials[blockIdx.x] + ((t == 0) ? 0 : lds[t - 1]);
    if (base + 0 < NTOT) { rp[base + 0] = p; cur[base + 0] = p; p += v0; }
    if (base + 1 < NTOT) { rp[base + 1] = p; cur[base + 1] = p; p += v1; }
    if (base + 2 < NTOT) { rp[base + 2] = p; cur[base + 2] = p; p += v2; }
    if (base + 3 < NTOT) { rp[base + 3] = p; cur[base + 3] = p; }
}

// ---------------- combined CSR fill (packed {src, weight} AoS) ----------------
// One 8-byte scattered store per edge instead of two 4-byte stores to two
// different arrays: halves the number of dirty-line touches.
__global__ __launch_bounds__(256) void fill_kernel(
    const int* __restrict__ ei_iu, const float* __restrict__ ew_iu,
    const int* __restrict__ ei_ui, const float* __restrict__ ew_ui,
    int* __restrict__ cur, int2* __restrict__ csr,
    int E, int NU)
{
    int t = blockIdx.x * blockDim.x + threadIdx.x;
    if (t < E) {
        int src = ei_iu[t];
        int wbits = __float_as_int(ew_iu[t]);
        int pos = atomicAdd(&cur[ei_iu[E + t]], 1);
        csr[pos] = make_int2(src, wbits);
    } else if (t < 2 * E) {
        int e = t - E;
        int src = ei_ui[e];
        int wbits = __float_as_int(ew_ui[e]);
        int pos = atomicAdd(&cur[NU + ei_ui[E + e]], 1);
        csr[pos] = make_int2(src, wbits);
    }
}

// ---------------- fused gather-aggregate + mean + residual + LN (+relu) ----------------
// one 64-lane wave per dst row; 2 edges processed per iteration;
// lane = 32*sub + ch_lane; lane holds channels [4*ch_lane .. 4*ch_lane+3] of edge `sub`.
__global__ __launch_bounds__(256) void sage_ln_kernel(
    const float* __restrict__ x_src,
    const float* __restrict__ x_dst,
    const int* __restrict__ rp,
    const int2* __restrict__ csr,
    const float* __restrict__ lnw,
    const float* __restrict__ lnb,
    float* __restrict__ out,
    int N, int do_relu)
{
    int row  = blockIdx.x * 4 + (threadIdx.x >> 6);
    int lane = threadIdx.x & 63;
    int sub  = lane >> 5;       // which of the 2 edges this half-wave handles
    int cl   = lane & 31;       // channel-group lane (float4 => 4 channels)
    if (row >= N) return;
    int start = rp[row];
    int end   = rp[row + 1];

    float4 acc = {0.f, 0.f, 0.f, 0.f};
    for (int base = start; base < end; base += 64) {
        int idx = base + lane;
        int src = 0;
        float w = 0.0f;
        if (idx < end) {
            int2 ev = csr[idx];
            src = ev.x;
            w   = __int_as_float(ev.y);
        }
        int n = min(64, end - base);
        for (int j = 0; 2 * j < n; ++j) {
            int   sj = __shfl(src, 2 * j + sub, 64);
            float wj = __shfl(w,   2 * j + sub, 64);
            float4 v = ((const float4*)(x_src + (size_t)sj * C))[cl];
            acc.x += v.x * wj;
            acc.y += v.y * wj;
            acc.z += v.z * wj;
            acc.w += v.w * wj;
        }
    }
    // combine the two half-wave partial sums (both halves end with full sum)
    acc.x += __shfl_xor(acc.x, 32, 64);
    acc.y += __shfl_xor(acc.y, 32, 64);
    acc.z += __shfl_xor(acc.z, 32, 64);
    acc.w += __shfl_xor(acc.w, 32, 64);

    float inv = 1.0f / fmaxf((float)(end - start), 1.0f);
    float4 xd = ((const float4*)(x_dst + (size_t)row * C))[cl];
    float4 v;
    v.x = acc.x * inv + xd.x;
    v.y = acc.y * inv + xd.y;
    v.z = acc.z * inv + xd.z;
    v.w = acc.w * inv + xd.w;

    float sum = v.x + v.y + v.z + v.w;
    float sq  = v.x * v.x + v.y * v.y + v.z * v.z + v.w * v.w;
    #pragma unroll
    for (int off = 16; off > 0; off >>= 1) {
        sum += __shfl_xor(sum, off, 64);
        sq  += __shfl_xor(sq,  off, 64);
    }
    float mu   = sum * (1.0f / C);
    float var  = sq * (1.0f / C) - mu * mu;
    float rstd = rsqrtf(var + EPS);

    float4 wv = ((const float4*)lnw)[cl];
    float4 bv = ((const float4*)lnb)[cl];
    float4 o;
    o.x = (v.x - mu) * rstd * wv.x + bv.x;
    o.y = (v.y - mu) * rstd * wv.y + bv.y;
    o.z = (v.z - mu) * rstd * wv.z + bv.z;
    o.w = (v.w - mu) * rstd * wv.w + bv.w;
    if (do_relu) {
        o.x = fmaxf(o.x, 0.f); o.y = fmaxf(o.y, 0.f);
        o.z = fmaxf(o.z, 0.f); o.w = fmaxf(o.w, 0.f);
    }
    if (sub == 0) ((float4*)(out + (size_t)row * C))[cl] = o;
}

extern "C" void kernel_launch(void* const* d_in, const int* in_sizes, int n_in,
                              void* d_out, int out_size, void* d_ws, size_t ws_size,
                              hipStream_t stream)
{
    const float* x_user = (const float*)d_in[0];
    const float* x_item = (const float*)d_in[1];
    const float* ew_ui  = (const float*)d_in[2];
    const float* ew_iu  = (const float*)d_in[3];
    const float* lnwu0  = (const float*)d_in[4];
    const float* lnbu0  = (const float*)d_in[5];
    const float* lnwu1  = (const float*)d_in[6];
    const float* lnbu1  = (const float*)d_in[7];
    const float* lnwi0  = (const float*)d_in[8];
    const float* lnbi0  = (const float*)d_in[9];
    const float* lnwi1  = (const float*)d_in[10];
    const float* lnbi1  = (const float*)d_in[11];
    const int*   ei_ui  = (const int*)d_in[12];  // src=user, dst=item
    const int*   ei_iu  = (const int*)d_in[13];  // src=item, dst=user

    const int NU = in_sizes[0] / C;
    const int NI = in_sizes[1] / C;
    const int E  = in_sizes[2];
    const int NTOT = NU + NI;

    float* out   = (float*)d_out;
    float* out_u = out;
    float* out_i = out + (size_t)NU * C;

    // ---- ws layout ----
    char* p = (char*)d_ws;
    float* act_u   = (float*)p;    p += (size_t)NU * C * sizeof(float);
    int2*  csr     = (int2*)p;     p += (size_t)2 * E * sizeof(int2);
    int*   cnt     = (int*)p;      p += (size_t)NTOT * sizeof(int);
    int*   rp      = (int*)p;      p += (size_t)(NTOT + 1) * sizeof(int);
    int*   cur     = (int*)p;      p += (size_t)NTOT * sizeof(int);
    int*   partials = (int*)p;     p += (size_t)1024 * sizeof(int);

    const int NPART = (NTOT + SCAN_TILE - 1) / SCAN_TILE;

    dim3 eblk(256), egrd((2 * E + 255) / 256);
    dim3 fblk(256);
    dim3 fgrd_u((NU + 3) / 4), fgrd_i((NI + 3) / 4);

    // ---- build combined CSR (by destination bucket) ----
    hipMemsetAsync(cnt, 0, (size_t)NTOT * sizeof(int), stream);
    count_kernel<<<egrd, eblk, 0, stream>>>(ei_iu, ei_ui, cnt, E, NU);
    scan_partials<<<NPART, 1024, 0, stream>>>(cnt, partials, NTOT);
    scan_spine<<<1, 1024, 0, stream>>>(partials, rp, NPART, NTOT);
    scan_write<<<NPART, 1024, 0, stream>>>(cnt, partials, rp, cur, NTOT);
    fill_kernel<<<egrd, eblk, 0, stream>>>(ei_iu, ew_iu, ei_ui, ew_ui,
                                           cur, csr, E, NU);

    // ---- layer 0 ----
    sage_ln_kernel<<<fgrd_u, fblk, 0, stream>>>(x_item, x_user, rp, csr,
                                                lnwu0, lnbu0, act_u, NU, 1);
    sage_ln_kernel<<<fgrd_i, fblk, 0, stream>>>(x_user, x_item, rp + NU, csr,
                                                lnwi0, lnbi0, out_i, NI, 1);

    // ---- layer 1 (user kernel MUST precede item kernel: it gathers from out_i) ----
    sage_ln_kernel<<<fgrd_u, fblk, 0, stream>>>(out_i, act_u, rp, csr,
                                                lnwu1, lnbu1, out_u, NU, 0);
    sage_ln_kernel<<<fgrd_i, fblk, 0, stream>>>(act_u, out_i, rp + NU, csr,
                                                lnwi1, lnbi1, out_i, NI, 0);
}

// Round 2
// 750.465 us; speedup vs baseline: 1.3564x; 1.3564x over previous
//
#include <hip/hip_runtime.h>

#define C 128
#define EPS 1e-5f

// ---- two-level CSR build parameters ----
#define NPC        1024      // nodes per coarse bucket (power of 2)
#define NPC_SHIFT  10
#define SRC_BITS   17        // src ids < 131072
#define SRC_MASK   0x1FFFF
#define TILE       4096      // edges per bin-kernel block
#define BTH        512       // threads for bin/count kernels

// ================= level-0: coarse histogram =================
__global__ __launch_bounds__(BTH) void coarse_count_kernel(
    const int* __restrict__ ei_iu, const int* __restrict__ ei_ui,
    int* __restrict__ coarse_cnt, int E, int NU)
{
    __shared__ int hist[512];
    int tid = threadIdx.x;
    hist[tid] = 0;
    __syncthreads();
    int base = blockIdx.x * TILE;
    #pragma unroll
    for (int k = 0; k < TILE / BTH; ++k) {
        int t = base + tid + k * BTH;
        if (t < 2 * E) {
            int node;
            if (t < E) node = ei_iu[E + t];
            else       node = NU + ei_ui[E + (t - E)];
            atomicAdd(&hist[node >> NPC_SHIFT], 1);
        }
    }
    __syncthreads();
    if (hist[tid] > 0) atomicAdd(&coarse_cnt[tid], hist[tid]);
}

// ================= level-0b: tiny scan over coarse buckets =================
__global__ __launch_bounds__(512) void coarse_scan_kernel(
    const int* __restrict__ coarse_cnt, int* __restrict__ coarse_rp,
    int* __restrict__ coarse_cur, int* __restrict__ rp,
    int NCOARSE, int NTOT, int total)
{
    __shared__ int lds[512];
    int t = threadIdx.x;
    int v0 = (t < NCOARSE) ? coarse_cnt[t] : 0;
    lds[t] = v0;
    __syncthreads();
    for (int off = 1; off < 512; off <<= 1) {
        int v = (t >= off) ? lds[t - off] : 0;
        __syncthreads();
        lds[t] += v;
        __syncthreads();
    }
    int excl = lds[t] - v0;
    if (t < NCOARSE) { coarse_rp[t] = excl; coarse_cur[t] = excl; }
    if (t == 0) rp[NTOT] = total;
}

// ================= level-1: bin edges by coarse bucket (LDS write-combine) ==
// element = u64: low 32 = packed (node_local<<17 | src), high 32 = weight bits
__global__ __launch_bounds__(BTH) void bin_kernel(
    const int* __restrict__ ei_iu, const float* __restrict__ ew_iu,
    const int* __restrict__ ei_ui, const float* __restrict__ ew_ui,
    int* __restrict__ coarse_cur, unsigned long long* __restrict__ binned,
    int E, int NU)
{
    __shared__ int hist[512];
    __shared__ int loff[512];
    __shared__ int cursor[512];
    __shared__ int gbase[512];
    __shared__ unsigned long long staged[TILE];   // 32 KB
    __shared__ unsigned short sbucket[TILE];      // 8 KB

    int tid = threadIdx.x;
    int base = blockIdx.x * TILE;
    hist[tid] = 0;
    __syncthreads();

    int cb[TILE / BTH];
    unsigned long long val[TILE / BTH];
    #pragma unroll
    for (int k = 0; k < TILE / BTH; ++k) {
        int t = base + tid + k * BTH;
        cb[k] = -1;
        if (t < 2 * E) {
            int node, src; float w;
            if (t < E) { node = ei_iu[E + t]; src = ei_iu[t]; w = ew_iu[t]; }
            else { int e = t - E; node = NU + ei_ui[E + e]; src = ei_ui[e]; w = ew_ui[e]; }
            cb[k] = node >> NPC_SHIFT;
            unsigned packed = ((unsigned)(node & (NPC - 1)) << SRC_BITS) | (unsigned)src;
            val[k] = ((unsigned long long)__float_as_uint(w) << 32) | packed;
            atomicAdd(&hist[cb[k]], 1);
        }
    }
    __syncthreads();

    // in-place inclusive scan of hist -> loff (then make exclusive)
    loff[tid] = hist[tid];
    __syncthreads();
    for (int off = 1; off < 512; off <<= 1) {
        int v = (tid >= off) ? loff[tid - off] : 0;
        __syncthreads();
        loff[tid] += v;
        __syncthreads();
    }
    int excl = loff[tid] - hist[tid];
    __syncthreads();
    loff[tid] = excl;
    cursor[tid] = excl;
    if (hist[tid] > 0) gbase[tid] = atomicAdd(&coarse_cur[tid], hist[tid]);
    __syncthreads();

    // stage into LDS grouped by coarse bucket
    #pragma unroll
    for (int k = 0; k < TILE / BTH; ++k) {
        if (cb[k] >= 0) {
            int j = atomicAdd(&cursor[cb[k]], 1);
            staged[j] = val[k];
            sbucket[j] = (unsigned short)cb[k];
        }
    }
    __syncthreads();

    // coalesced flush: consecutive j are mostly the same bucket -> long runs
    int total = min(TILE, 2 * E - base);
    for (int j = tid; j < total; j += BTH) {
        int b = sbucket[j];
        binned[gbase[b] + (j - loff[b])] = staged[j];
    }
}

// ================= level-2: per-coarse-bucket counting sort -> rp + csr =====
__global__ __launch_bounds__(512) void build_kernel(
    const unsigned long long* __restrict__ binned,
    const int* __restrict__ coarse_cnt, const int* __restrict__ coarse_rp,
    int* __restrict__ rp, int2* __restrict__ csr, int NTOT)
{
    __shared__ int hist[NPC];
    __shared__ int cur[NPC];
    __shared__ int ps[512];
    int cb  = blockIdx.x;
    int tid = threadIdx.x;
    int cnt  = coarse_cnt[cb];
    int base = coarse_rp[cb];
    int lo   = cb << NPC_SHIFT;
    int ncnt = min(NPC, NTOT - lo);

    hist[tid] = 0; hist[tid + 512] = 0;
    __syncthreads();
    for (int j = tid; j < cnt; j += 512) {
        unsigned packed = (unsigned)(binned[base + j] & 0xFFFFFFFFu);
        atomicAdd(&hist[packed >> SRC_BITS], 1);
    }
    __syncthreads();

    // scan over 1024 = pair-per-thread + 512-wide LDS scan
    int h0 = hist[2 * tid], h1 = hist[2 * tid + 1];
    ps[tid] = h0 + h1;
    __syncthreads();
    for (int off = 1; off < 512; off <<= 1) {
        int v = (tid >= off) ? ps[tid - off] : 0;
        __syncthreads();
        ps[tid] += v;
        __syncthreads();
    }
    int pexcl = ps[tid] - (h0 + h1);
    int r0 = base + pexcl;
    int r1 = r0 + h0;
    if (2 * tid < ncnt)     rp[lo + 2 * tid] = r0;
    if (2 * tid + 1 < ncnt) rp[lo + 2 * tid + 1] = r1;
    cur[2 * tid] = r0;
    cur[2 * tid + 1] = r1;
    __syncthreads();

    // scatter into final CSR: all writes land in a ~cnt*8B contiguous window
    for (int j = tid; j < cnt; j += 512) {
        unsigned long long v = binned[base + j];
        unsigned packed = (unsigned)(v & 0xFFFFFFFFu);
        int pos = atomicAdd(&cur[packed >> SRC_BITS], 1);
        csr[pos] = make_int2((int)(packed & SRC_MASK), (int)(v >> 32));
    }
}

// ---------------- fused gather-aggregate + mean + residual + LN (+relu) ----
__global__ __launch_bounds__(256) void sage_ln_kernel(
    const float* __restrict__ x_src,
    const float* __restrict__ x_dst,
    const int* __restrict__ rp,
    const int2* __restrict__ csr,
    const float* __restrict__ lnw,
    const float* __restrict__ lnb,
    float* __restrict__ out,
    int N, int do_relu)
{
    int row  = blockIdx.x * 4 + (threadIdx.x >> 6);
    int lane = threadIdx.x & 63;
    int sub  = lane >> 5;
    int cl   = lane & 31;
    if (row >= N) return;
    int start = rp[row];
    int end   = rp[row + 1];

    float4 acc = {0.f, 0.f, 0.f, 0.f};
    for (int base = start; base < end; base += 64) {
        int idx = base + lane;
        int src = 0;
        float w = 0.0f;
        if (idx < end) {
            int2 ev = csr[idx];
            src = ev.x;
            w   = __int_as_float(ev.y);
        }
        int n = min(64, end - base);
        for (int j = 0; 2 * j < n; ++j) {
            int   sj = __shfl(src, 2 * j + sub, 64);
            float wj = __shfl(w,   2 * j + sub, 64);
            float4 v = ((const float4*)(x_src + (size_t)sj * C))[cl];
            acc.x += v.x * wj;
            acc.y += v.y * wj;
            acc.z += v.z * wj;
            acc.w += v.w * wj;
        }
    }
    acc.x += __shfl_xor(acc.x, 32, 64);
    acc.y += __shfl_xor(acc.y, 32, 64);
    acc.z += __shfl_xor(acc.z, 32, 64);
    acc.w += __shfl_xor(acc.w, 32, 64);

    float inv = 1.0f / fmaxf((float)(end - start), 1.0f);
    float4 xd = ((const float4*)(x_dst + (size_t)row * C))[cl];
    float4 v;
    v.x = acc.x * inv + xd.x;
    v.y = acc.y * inv + xd.y;
    v.z = acc.z * inv + xd.z;
    v.w = acc.w * inv + xd.w;

    float sum = v.x + v.y + v.z + v.w;
    float sq  = v.x * v.x + v.y * v.y + v.z * v.z + v.w * v.w;
    #pragma unroll
    for (int off = 16; off > 0; off >>= 1) {
        sum += __shfl_xor(sum, off, 64);
        sq  += __shfl_xor(sq,  off, 64);
    }
    float mu   = sum * (1.0f / C);
    float var  = sq * (1.0f / C) - mu * mu;
    float rstd = rsqrtf(var + EPS);

    float4 wv = ((const float4*)lnw)[cl];
    float4 bv = ((const float4*)lnb)[cl];
    float4 o;
    o.x = (v.x - mu) * rstd * wv.x + bv.x;
    o.y = (v.y - mu) * rstd * wv.y + bv.y;
    o.z = (v.z - mu) * rstd * wv.z + bv.z;
    o.w = (v.w - mu) * rstd * wv.w + bv.w;
    if (do_relu) {
        o.x = fmaxf(o.x, 0.f); o.y = fmaxf(o.y, 0.f);
        o.z = fmaxf(o.z, 0.f); o.w = fmaxf(o.w, 0.f);
    }
    if (sub == 0) ((float4*)(out + (size_t)row * C))[cl] = o;
}

extern "C" void kernel_launch(void* const* d_in, const int* in_sizes, int n_in,
                              void* d_out, int out_size, void* d_ws, size_t ws_size,
                              hipStream_t stream)
{
    const float* x_user = (const float*)d_in[0];
    const float* x_item = (const float*)d_in[1];
    const float* ew_ui  = (const float*)d_in[2];
    const float* ew_iu  = (const float*)d_in[3];
    const float* lnwu0  = (const float*)d_in[4];
    const float* lnbu0  = (const float*)d_in[5];
    const float* lnwu1  = (const float*)d_in[6];
    const float* lnbu1  = (const float*)d_in[7];
    const float* lnwi0  = (const float*)d_in[8];
    const float* lnbi0  = (const float*)d_in[9];
    const float* lnwi1  = (const float*)d_in[10];
    const float* lnbi1  = (const float*)d_in[11];
    const int*   ei_ui  = (const int*)d_in[12];  // src=user, dst=item
    const int*   ei_iu  = (const int*)d_in[13];  // src=item, dst=user

    const int NU = in_sizes[0] / C;
    const int NI = in_sizes[1] / C;
    const int E  = in_sizes[2];
    const int NTOT = NU + NI;
    const int NCOARSE = (NTOT + NPC - 1) >> NPC_SHIFT;   // <= 512

    float* out   = (float*)d_out;
    float* out_u = out;
    float* out_i = out + (size_t)NU * C;

    // ---- ws layout ----
    // binned aliases act_u: binned is dead before the first sage writes act_u.
    char* p = (char*)d_ws;
    float* act_u = (float*)p;                 p += (size_t)NU * C * sizeof(float);
    unsigned long long* binned = (unsigned long long*)act_u;
    int2*  csr       = (int2*)p;              p += (size_t)2 * E * sizeof(int2);
    int*   rp        = (int*)p;               p += (size_t)(NTOT + 1) * sizeof(int);
    int*   coarse_cnt = (int*)p;              p += 512 * sizeof(int);
    int*   coarse_rp  = (int*)p;              p += 512 * sizeof(int);
    int*   coarse_cur = (int*)p;              p += 512 * sizeof(int);

    const int NTILE = (2 * E + TILE - 1) / TILE;

    dim3 fblk(256);
    dim3 fgrd_u((NU + 3) / 4), fgrd_i((NI + 3) / 4);

    // ---- build CSR via two-level coarse-bucket sort (write-coalesced) ----
    hipMemsetAsync(coarse_cnt, 0, 512 * sizeof(int), stream);
    coarse_count_kernel<<<NTILE, BTH, 0, stream>>>(ei_iu, ei_ui, coarse_cnt, E, NU);
    coarse_scan_kernel<<<1, 512, 0, stream>>>(coarse_cnt, coarse_rp, coarse_cur,
                                              rp, NCOARSE, NTOT, 2 * E);
    bin_kernel<<<NTILE, BTH, 0, stream>>>(ei_iu, ew_iu, ei_ui, ew_ui,
                                          coarse_cur, binned, E, NU);
    build_kernel<<<NCOARSE, 512, 0, stream>>>(binned, coarse_cnt, coarse_rp,
                                              rp, csr, NTOT);

    // ---- layer 0 ----
    sage_ln_kernel<<<fgrd_u, fblk, 0, stream>>>(x_item, x_user, rp, csr,
                                                lnwu0, lnbu0, act_u, NU, 1);
    sage_ln_kernel<<<fgrd_i, fblk, 0, stream>>>(x_user, x_item, rp + NU, csr,
                                                lnwi0, lnbi0, out_i, NI, 1);

    // ---- layer 1 (user kernel MUST precede item kernel: it gathers from out_i) ----
    sage_ln_kernel<<<fgrd_u, fblk, 0, stream>>>(out_i, act_u, rp, csr,
                                                lnwu1, lnbu1, out_u, NU, 0);
    sage_ln_kernel<<<fgrd_i, fblk, 0, stream>>>(act_u, out_i, rp + NU, csr,
                                                lnwi1, lnbi1, out_i, NI, 0);
}